// Round 1
// baseline (379.238 us; speedup 1.0000x reference)
//
#include <hip/hip_runtime.h>
#include <hip/hip_bf16.h>

typedef __hip_bfloat16 bf16;
typedef __attribute__((ext_vector_type(4))) float f32x4;
typedef __attribute__((ext_vector_type(8))) short s16x8;
typedef __attribute__((ext_vector_type(4))) unsigned short u16x4;

#define NB 64
#define NT 197
#define DIM 768
#define NH 12
#define HQKV 3072
#define DH 1536
#define DV 128
#define MREAL (NB*NT)      // 12608
#define MPAD 12672         // 99*128
#define KPAD 224           // padded key count (14*16)
#define CNT ((float)MREAL)

__device__ __forceinline__ float bf2f(bf16 v) { return __bfloat162float(v); }
__device__ __forceinline__ bf16  f2bf(float v){ return __float2bfloat16(v); }

// async global->LDS, 16B per lane; LDS dest must be wave-uniform base (HW adds lane*16)
__device__ __forceinline__ void async16(const bf16* g, bf16* l) {
  __builtin_amdgcn_global_load_lds((const __attribute__((address_space(1))) void*)g,
                                   (__attribute__((address_space(3))) void*)l, 16, 0, 0);
}

// ---------------- prep: f32->bf16 converts, zero pads/stats/cls ----------------
__global__ void prep_kernel(const float* __restrict__ x, const float* __restrict__ qkv_w,
                            const float* __restrict__ proj_w,
                            bf16* __restrict__ xb, bf16* __restrict__ wqkvb,
                            bf16* __restrict__ wprojb, bf16* __restrict__ act,
                            float* __restrict__ statq, float* __restrict__ statp,
                            float* __restrict__ cls)
{
  const int stride = gridDim.x * blockDim.x;
  const int tid = blockIdx.x * blockDim.x + threadIdx.x;
  for (int i = tid; i < MPAD*DIM; i += stride) {
    int r = i / DIM;
    xb[i] = f2bf(r < MREAL ? x[i] : 0.f);
  }
  for (int i = tid; i < HQKV*DIM; i += stride) wqkvb[i] = f2bf(qkv_w[i]);
  for (int i = tid; i < DIM*DH;   i += stride) wprojb[i] = f2bf(proj_w[i]);
  for (int i = tid; i < (MPAD-MREAL)*DH; i += stride) act[(size_t)MREAL*DH + i] = f2bf(0.f);
  for (int i = tid; i < 2*HQKV; i += stride) statq[i] = 0.f;
  for (int i = tid; i < 2*DIM;  i += stride) statp[i] = 0.f;
  for (int i = tid; i < NB*(NT-1); i += stride) cls[i] = 0.f;
}

// ---------------- GEMM C[m][n] = sum_k A[m][k]*Bw[n][k], + per-col sum/sumsq ----------------
// 128x128 tile, BK=32, 256 threads (4 waves, each 64x64 quadrant of 4x4 16x16 frags)
template<int K, int NTILES>
__global__ __launch_bounds__(256)
void gemm_bt(const bf16* __restrict__ A, const bf16* __restrict__ Bw,
             bf16* __restrict__ C, float* __restrict__ stats, int Ncols)
{
  __shared__ bf16 As[128*32];
  __shared__ bf16 Bs[128*32];
  const int bn = blockIdx.x % NTILES;
  const int bm = blockIdx.x / NTILES;
  const int t = threadIdx.x;
  const int wave = t >> 6, lane = t & 63;
  const int wm = wave >> 1, wn = wave & 1;
  const int l15 = lane & 15, l4 = lane >> 4;

  f32x4 acc[4][4] = {};

  const bf16* aBase = A  + (size_t)(bm*128 + (t>>2))*K + (t&3)*8;
  const bf16* bBase = Bw + (size_t)(bn*128 + (t>>2))*K + (t&3)*8;
  bf16* asD0 = &As[wave*512];        // per-wave uniform LDS dest bases
  bf16* asD1 = &As[2048 + wave*512];
  bf16* bsD0 = &Bs[wave*512];
  bf16* bsD1 = &Bs[2048 + wave*512];

  for (int kt = 0; kt < K/32; ++kt) {
    const bf16* ag = aBase + kt*32;
    const bf16* bg = bBase + kt*32;
    async16(ag, asD0);
    async16(ag + (size_t)64*K, asD1);
    async16(bg, bsD0);
    async16(bg + (size_t)64*K, bsD1);
    __syncthreads();   // drains vmcnt before barrier
    s16x8 af[4], bfr[4];
#pragma unroll
    for (int i = 0; i < 4; ++i) af[i]  = *(const s16x8*)&As[(wm*64 + i*16 + l15)*32 + l4*8];
#pragma unroll
    for (int i = 0; i < 4; ++i) bfr[i] = *(const s16x8*)&Bs[(wn*64 + i*16 + l15)*32 + l4*8];
#pragma unroll
    for (int im = 0; im < 4; ++im)
#pragma unroll
      for (int in = 0; in < 4; ++in)
        acc[im][in] = __builtin_amdgcn_mfma_f32_16x16x32_bf16(af[im], bfr[in], acc[im][in], 0, 0, 0);
    __syncthreads();
  }

  const size_t row0 = (size_t)bm*128 + wm*64;
  const int col0 = bn*128 + wn*64;
#pragma unroll
  for (int in = 0; in < 4; ++in) {
    const int col = col0 + in*16 + l15;
    float s = 0.f, sq = 0.f;
#pragma unroll
    for (int im = 0; im < 4; ++im) {
#pragma unroll
      for (int j = 0; j < 4; ++j) {
        float v = acc[im][in][j];
        C[(row0 + im*16 + l4*4 + j)*Ncols + col] = f2bf(v);
        s += v; sq += v*v;   // padded rows are exact zeros -> no stat pollution
      }
    }
    s  += __shfl_xor(s, 16);  s  += __shfl_xor(s, 32);
    sq += __shfl_xor(sq, 16); sq += __shfl_xor(sq, 32);
    if (l4 == 0) { atomicAdd(&stats[col], s); atomicAdd(&stats[Ncols + col], sq); }
  }
}

// ---------------- BN stats -> per-feature scale/bias ----------------
__global__ void finalize_stats(const float* __restrict__ stats, const float* __restrict__ g,
                               const float* __restrict__ bb, float* __restrict__ sb, int F)
{
  int f = blockIdx.x * blockDim.x + threadIdx.x;
  if (f >= F) return;
  float m   = stats[f] / CNT;
  float var = stats[F + f] / CNT - m*m;
  float scl = g[f] / sqrtf(var + 1e-5f);
  sb[f] = scl;
  sb[F + f] = bb[f] - m*scl;
}

// ---------------- fused attention per (b,h): BN-on-load, QK^T, softmax, cls, PV, hardswish ----------------
__global__ __launch_bounds__(256)
void attn_kernel(const bf16* __restrict__ qkv, const float* __restrict__ sb,
                 bf16* __restrict__ act, float* __restrict__ cls)
{
  __shared__ bf16 k_lds[KPAD*64];     // 28.0 KB  [key][feat]
  __shared__ bf16 vT_lds[DV*KPAD];    // 56.0 KB  [d][key]
  __shared__ bf16 q_lds[64*64];       //  8.0 KB  [q][feat] (chunk)
  __shared__ bf16 p_lds[64*KPAD];     // 28.0 KB  [q][key]  (chunk)

  const int bh = blockIdx.x;
  const int b = bh / NH, h = bh % NH;
  const int t = threadIdx.x;
  const int wave = t >> 6, lane = t & 63;
  const int l15 = lane & 15, l4 = lane >> 4;
  const size_t rowBase = (size_t)b * NT;
  const int fq = h*256, fk = fq + 64, fv = fq + 128;

  for (int i = t; i < KPAD*64; i += 256) {
    int r = i >> 6, c = i & 63;
    float v = 0.f;
    if (r < NT) { int f = fk + c; v = bf2f(qkv[(rowBase + r)*HQKV + f]) * sb[f] + sb[HQKV + f]; }
    k_lds[i] = f2bf(v);
  }
  for (int i = t; i < NT*DV; i += 256) {
    int r = i >> 7, c = i & 127;
    int f = fv + c;
    float v = bf2f(qkv[(rowBase + r)*HQKV + f]) * sb[f] + sb[HQKV + f];
    vT_lds[c*KPAD + r] = f2bf(v);
  }
  for (int i = t; i < DV*(KPAD-NT); i += 256) {
    int c = i / (KPAD-NT), r = NT + i % (KPAD-NT);
    vT_lds[c*KPAD + r] = f2bf(0.f);
  }
  __syncthreads();

  for (int qc = 0; qc < 4; ++qc) {
    for (int i = t; i < 64*64; i += 256) {
      int r = i >> 6, c = i & 63;
      int q = qc*64 + r;
      float v = 0.f;
      if (q < NT) { int f = fq + c; v = (bf2f(qkv[(rowBase + q)*HQKV + f]) * sb[f] + sb[HQKV + f]) * 0.125f; }
      q_lds[i] = f2bf(v);  // SCALE folded into q
    }
    __syncthreads();

    // scores: wave handles 16 queries x 224 keys; 14 col-tiles, K=64 in 2 MFMA steps
    f32x4 scr[14] = {};
    s16x8 aq0 = *(const s16x8*)&q_lds[(wave*16 + l15)*64 + l4*8];
    s16x8 aq1 = *(const s16x8*)&q_lds[(wave*16 + l15)*64 + 32 + l4*8];
#pragma unroll
    for (int kt = 0; kt < 14; ++kt) {
      s16x8 bk0 = *(const s16x8*)&k_lds[(kt*16 + l15)*64 + l4*8];
      s16x8 bk1 = *(const s16x8*)&k_lds[(kt*16 + l15)*64 + 32 + l4*8];
      scr[kt] = __builtin_amdgcn_mfma_f32_16x16x32_bf16(aq0, bk0, scr[kt], 0, 0, 0);
      scr[kt] = __builtin_amdgcn_mfma_f32_16x16x32_bf16(aq1, bk1, scr[kt], 0, 0, 0);
    }
    // softmax: lane holds rows l4*4+j, cols kt*16+l15; row-group = 16 lanes (xor 1,2,4,8)
    float mx[4] = {-1e30f, -1e30f, -1e30f, -1e30f}, sm[4];
#pragma unroll
    for (int kt = 0; kt < 14; ++kt) {
      int colv = kt*16 + l15;
#pragma unroll
      for (int j = 0; j < 4; ++j) {
        if (colv >= NT) scr[kt][j] = -1e30f;
        mx[j] = fmaxf(mx[j], scr[kt][j]);
      }
    }
#pragma unroll
    for (int j = 0; j < 4; ++j) {
      mx[j] = fmaxf(mx[j], __shfl_xor(mx[j], 1));
      mx[j] = fmaxf(mx[j], __shfl_xor(mx[j], 2));
      mx[j] = fmaxf(mx[j], __shfl_xor(mx[j], 4));
      mx[j] = fmaxf(mx[j], __shfl_xor(mx[j], 8));
      sm[j] = 0.f;
    }
#pragma unroll
    for (int kt = 0; kt < 14; ++kt)
#pragma unroll
      for (int j = 0; j < 4; ++j) { float e = __expf(scr[kt][j] - mx[j]); scr[kt][j] = e; sm[j] += e; }
#pragma unroll
    for (int j = 0; j < 4; ++j) {
      sm[j] += __shfl_xor(sm[j], 1);
      sm[j] += __shfl_xor(sm[j], 2);
      sm[j] += __shfl_xor(sm[j], 4);
      sm[j] += __shfl_xor(sm[j], 8);
      sm[j] = 1.f / sm[j];
    }
    // cls-row reduction: query 0 lives in qc==0, wave==0, l4==0, j==0
    if (qc == 0 && wave == 0 && l4 == 0) {
#pragma unroll
      for (int kt = 0; kt < 14; ++kt) {
        int colv = kt*16 + l15;
        if (colv >= 1 && colv < NT)
          atomicAdd(&cls[b*(NT-1) + colv - 1], scr[kt][0] * sm[0] * (1.f/NH));
      }
    }
#pragma unroll
    for (int kt = 0; kt < 14; ++kt) {
      int colv = kt*16 + l15;
#pragma unroll
      for (int j = 0; j < 4; ++j)
        p_lds[(wave*16 + l4*4 + j)*KPAD + colv] = f2bf(scr[kt][j] * sm[j]);
    }
    __syncthreads();

    // PV: out[16q][128d] per wave; masked keys have p==0 exactly
    f32x4 ao[8] = {};
#pragma unroll
    for (int ks = 0; ks < 7; ++ks) {
      s16x8 ap = *(const s16x8*)&p_lds[(wave*16 + l15)*KPAD + ks*32 + l4*8];
#pragma unroll
      for (int dt = 0; dt < 8; ++dt) {
        s16x8 bv = *(const s16x8*)&vT_lds[(dt*16 + l15)*KPAD + ks*32 + l4*8];
        ao[dt] = __builtin_amdgcn_mfma_f32_16x16x32_bf16(ap, bv, ao[dt], 0, 0, 0);
      }
    }
#pragma unroll
    for (int dt = 0; dt < 8; ++dt) {
#pragma unroll
      for (int j = 0; j < 4; ++j) {
        int q = qc*64 + wave*16 + l4*4 + j;
        if (q < NT) {
          float v = ao[dt][j];
          float hs = v * fminf(fmaxf(v + 3.f, 0.f), 6.f) * (1.f/6.f);
          act[(rowBase + q)*DH + h*DV + dt*16 + l15] = f2bf(hs);
        }
      }
    }
    __syncthreads();
  }
}

// ---------------- final BN apply -> f32 out ----------------
__global__ void apply_bn(const bf16* __restrict__ y, const float* __restrict__ sb,
                         float* __restrict__ out)
{
  const int stride = gridDim.x * blockDim.x;
  for (int i = blockIdx.x * blockDim.x + threadIdx.x; i < MREAL*DIM/4; i += stride) {
    int c = (i*4) % DIM;
    u16x4 yv = *(const u16x4*)&y[(size_t)i*4];
    float4 o;
    o.x = __builtin_bit_cast(float, (unsigned)yv.x << 16) * sb[c]     + sb[DIM + c];
    o.y = __builtin_bit_cast(float, (unsigned)yv.y << 16) * sb[c + 1] + sb[DIM + c + 1];
    o.z = __builtin_bit_cast(float, (unsigned)yv.z << 16) * sb[c + 2] + sb[DIM + c + 2];
    o.w = __builtin_bit_cast(float, (unsigned)yv.w << 16) * sb[c + 3] + sb[DIM + c + 3];
    *(float4*)&out[(size_t)i*4] = o;
  }
}

extern "C" void kernel_launch(void* const* d_in, const int* in_sizes, int n_in,
                              void* d_out, int out_size, void* d_ws, size_t ws_size,
                              hipStream_t stream)
{
  const float* x      = (const float*)d_in[0];
  const float* qkv_w  = (const float*)d_in[1];
  const float* qkv_g  = (const float*)d_in[2];
  const float* qkv_b  = (const float*)d_in[3];
  const float* proj_w = (const float*)d_in[4];
  const float* proj_g = (const float*)d_in[5];
  const float* proj_b = (const float*)d_in[6];
  float* y_out   = (float*)d_out;
  float* cls_out = y_out + (size_t)MREAL * DIM;

  char* ws = (char*)d_ws;
  size_t off = 0;
  auto alloc = [&](size_t bytes) { void* p = ws + off; off += (bytes + 255) & ~(size_t)255; return p; };
  bf16* xb      = (bf16*)alloc((size_t)MPAD * DIM * 2);
  bf16* wqkvb   = (bf16*)alloc((size_t)HQKV * DIM * 2);
  bf16* wprojb  = (bf16*)alloc((size_t)DIM * DH * 2);
  bf16* qkv_raw = (bf16*)alloc((size_t)MPAD * HQKV * 2);
  bf16* act     = (bf16*)alloc((size_t)MPAD * DH * 2);
  bf16* y_raw   = (bf16*)alloc((size_t)MPAD * DIM * 2);
  float* statq  = (float*)alloc((size_t)2 * HQKV * 4);
  float* sbq    = (float*)alloc((size_t)2 * HQKV * 4);
  float* statp  = (float*)alloc((size_t)2 * DIM * 4);
  float* sbp    = (float*)alloc((size_t)2 * DIM * 4);

  prep_kernel<<<1024, 256, 0, stream>>>(x, qkv_w, proj_w, xb, wqkvb, wprojb, act,
                                        statq, statp, cls_out);
  gemm_bt<DIM, HQKV/128><<<(MPAD/128)*(HQKV/128), 256, 0, stream>>>(xb, wqkvb, qkv_raw, statq, HQKV);
  finalize_stats<<<HQKV/256, 256, 0, stream>>>(statq, qkv_g, qkv_b, sbq, HQKV);
  attn_kernel<<<NB*NH, 256, 0, stream>>>(qkv_raw, sbq, act, cls_out);
  gemm_bt<DH, DIM/128><<<(MPAD/128)*(DIM/128), 256, 0, stream>>>(act, wprojb, y_raw, statp, DIM);
  finalize_stats<<<DIM/256, 256, 0, stream>>>(statp, proj_g, proj_b, sbp, DIM);
  apply_bn<<<2048, 256, 0, stream>>>(y_raw, sbp, y_out);
}

// Round 2
// 324.340 us; speedup vs baseline: 1.1693x; 1.1693x over previous
//
#include <hip/hip_runtime.h>
#include <hip/hip_bf16.h>

typedef __hip_bfloat16 bf16;
typedef __attribute__((ext_vector_type(4))) float f32x4;
typedef __attribute__((ext_vector_type(8))) short s16x8;
typedef __attribute__((ext_vector_type(4))) unsigned short u16x4;

#define NB 64
#define NT 197
#define DIM 768
#define NH 12
#define HQKV 3072
#define DH 1536
#define DV 128
#define MREAL (NB*NT)      // 12608
#define MPAD 12672         // 99*128
#define KPAD 224           // padded key count
#define PSTR 232           // P-tile LDS row stride (224+8: bank-conflict-free)
#define CNT ((float)MREAL)

__device__ __forceinline__ float bf2f(bf16 v) { return __bfloat162float(v); }
__device__ __forceinline__ bf16  f2bf(float v){ return __float2bfloat16(v); }
__device__ __forceinline__ unsigned short f2bfu(float v){ return __builtin_bit_cast(unsigned short, __float2bfloat16(v)); }
__device__ __forceinline__ float u2f(unsigned short u){ return __builtin_bit_cast(float, (unsigned)u << 16); }

// async global->LDS, 16B per lane; LDS dest must be wave-uniform base (HW adds lane*16)
__device__ __forceinline__ void async16(const bf16* g, bf16* l) {
  __builtin_amdgcn_global_load_lds((const __attribute__((address_space(1))) void*)g,
                                   (__attribute__((address_space(3))) void*)l, 16, 0, 0);
}

// ---------------- prep: f32->bf16 converts, zero pads/stats/cls/vT-pad ----------------
__global__ void prep_kernel(const float* __restrict__ x, const float* __restrict__ qkv_w,
                            const float* __restrict__ proj_w,
                            bf16* __restrict__ xb, bf16* __restrict__ wqkvb,
                            bf16* __restrict__ wprojb, bf16* __restrict__ act,
                            bf16* __restrict__ vT,
                            float* __restrict__ statq, float* __restrict__ statp,
                            float* __restrict__ cls)
{
  const int stride = gridDim.x * blockDim.x;
  const int tid = blockIdx.x * blockDim.x + threadIdx.x;
  for (int i = tid; i < MPAD*DIM; i += stride) {
    int r = i / DIM;
    xb[i] = f2bf(r < MREAL ? x[i] : 0.f);
  }
  for (int i = tid; i < HQKV*DIM; i += stride) wqkvb[i] = f2bf(qkv_w[i]);
  for (int i = tid; i < DIM*DH;   i += stride) wprojb[i] = f2bf(proj_w[i]);
  for (int i = tid; i < (MPAD-MREAL)*DH; i += stride) act[(size_t)MREAL*DH + i] = f2bf(0.f);
  // zero V^T pad columns (keys 197..223) each launch: keeps replays deterministic/finite
  for (int i = tid; i < NB*NH*DV*(KPAD-NT); i += stride) {
    int r = i / (KPAD-NT), c = NT + (i - r*(KPAD-NT));
    vT[(size_t)r*KPAD + c] = f2bf(0.f);
  }
  for (int i = tid; i < 2*HQKV; i += stride) statq[i] = 0.f;
  for (int i = tid; i < 2*DIM;  i += stride) statp[i] = 0.f;
  for (int i = tid; i < NB*(NT-1); i += stride) cls[i] = 0.f;
}

// ---------------- GEMM C[m][n] = sum_k A[m][k]*Bw[n][k], + per-col sum/sumsq ----------------
// 128x128 tile, BK=32, 256 threads (4 waves). VT mode: odd col-tiles (v-features)
// write transposed V^T[b,h][d][tok] instead of C.
template<int K, int NTILES, bool VT>
__global__ __launch_bounds__(256)
void gemm_bt(const bf16* __restrict__ A, const bf16* __restrict__ Bw,
             bf16* __restrict__ C, bf16* __restrict__ vT,
             float* __restrict__ stats, int Ncols)
{
  __shared__ bf16 As[128*32];
  __shared__ bf16 Bs[128*32];
  const int bn = blockIdx.x % NTILES;
  const int bm = blockIdx.x / NTILES;
  const int t = threadIdx.x;
  const int wave = t >> 6, lane = t & 63;
  const int wm = wave >> 1, wn = wave & 1;
  const int l15 = lane & 15, l4 = lane >> 4;

  f32x4 acc[4][4] = {};

  const bf16* aBase = A  + (size_t)(bm*128 + (t>>2))*K + (t&3)*8;
  const bf16* bBase = Bw + (size_t)(bn*128 + (t>>2))*K + (t&3)*8;
  bf16* asD0 = &As[wave*512];
  bf16* asD1 = &As[2048 + wave*512];
  bf16* bsD0 = &Bs[wave*512];
  bf16* bsD1 = &Bs[2048 + wave*512];

  for (int kt = 0; kt < K/32; ++kt) {
    const bf16* ag = aBase + kt*32;
    const bf16* bg = bBase + kt*32;
    async16(ag, asD0);
    async16(ag + (size_t)64*K, asD1);
    async16(bg, bsD0);
    async16(bg + (size_t)64*K, bsD1);
    __syncthreads();
    s16x8 af[4], bfr[4];
#pragma unroll
    for (int i = 0; i < 4; ++i) af[i]  = *(const s16x8*)&As[(wm*64 + i*16 + l15)*32 + l4*8];
#pragma unroll
    for (int i = 0; i < 4; ++i) bfr[i] = *(const s16x8*)&Bs[(wn*64 + i*16 + l15)*32 + l4*8];
#pragma unroll
    for (int im = 0; im < 4; ++im)
#pragma unroll
      for (int in = 0; in < 4; ++in)
        acc[im][in] = __builtin_amdgcn_mfma_f32_16x16x32_bf16(af[im], bfr[in], acc[im][in], 0, 0, 0);
    __syncthreads();
  }

  const size_t row0 = (size_t)bm*128 + wm*64;
  const int col0 = bn*128 + wn*64;
  if (!VT || (bn & 1) == 0) {
#pragma unroll
    for (int in = 0; in < 4; ++in) {
      const int col = col0 + in*16 + l15;
      float s = 0.f, sq = 0.f;
#pragma unroll
      for (int im = 0; im < 4; ++im) {
#pragma unroll
        for (int j = 0; j < 4; ++j) {
          float v = acc[im][in][j];
          C[(row0 + im*16 + l4*4 + j)*Ncols + col] = f2bf(v);
          s += v; sq += v*v;
        }
      }
      s  += __shfl_xor(s, 16);  s  += __shfl_xor(s, 32);
      sq += __shfl_xor(sq, 16); sq += __shfl_xor(sq, 32);
      if (l4 == 0) { atomicAdd(&stats[col], s); atomicAdd(&stats[Ncols + col], sq); }
    }
  } else {
    const int hh = bn >> 1;   // head index (v half-tile)
#pragma unroll
    for (int in = 0; in < 4; ++in) {
      const int col = col0 + in*16 + l15;
      const int d = col & 127;
      float s = 0.f, sq = 0.f;
#pragma unroll
      for (int im = 0; im < 4; ++im) {
        const int r0 = (int)row0 + im*16 + l4*4;
#pragma unroll
        for (int j = 0; j < 4; ++j) { float v = acc[im][in][j]; s += v; sq += v*v; }
        if (r0 < MREAL) {   // r0 % 4 == 0, MREAL % 4 == 0 -> all 4 rows real
          int b2 = r0 / 197;
          int n0 = r0 - b2*197;
          if (n0 <= NT-4) {
            bf16* dst = vT + ((size_t)((b2*NH + hh)*DV + d))*KPAD + n0;
#pragma unroll
            for (int j = 0; j < 4; ++j) dst[j] = f2bf(acc[im][in][j]);
          } else {
#pragma unroll
            for (int j = 0; j < 4; ++j) {
              int r = r0 + j; int b3 = r / 197; int n = r - b3*197;
              vT[((size_t)((b3*NH + hh)*DV + d))*KPAD + n] = f2bf(acc[im][in][j]);
            }
          }
        }
      }
      s  += __shfl_xor(s, 16);  s  += __shfl_xor(s, 32);
      sq += __shfl_xor(sq, 16); sq += __shfl_xor(sq, 32);
      if (l4 == 0) { atomicAdd(&stats[col], s); atomicAdd(&stats[Ncols + col], sq); }
    }
  }
}

// ---------------- BN stats -> per-feature scale/bias (optionally fold softmax scale into q) ----
__global__ void finalize_stats(const float* __restrict__ stats, const float* __restrict__ g,
                               const float* __restrict__ bb, float* __restrict__ sb, int F,
                               int foldq)
{
  int f = blockIdx.x * blockDim.x + threadIdx.x;
  if (f >= F) return;
  float m   = stats[f] / CNT;
  float var = stats[F + f] / CNT - m*m;
  float scl = g[f] / sqrtf(var + 1e-5f);
  float bia = bb[f] - m*scl;
  if (foldq && (f & 255) < 64) { scl *= 0.125f; bia *= 0.125f; }
  sb[f] = scl;
  sb[F + f] = bia;
}

// ---------------- apply BN in-place to Q/K of qkv_raw and to V^T ----------------
#define NQK (MREAL*NH*16)            // 8-elem groups in q/k region
#define NVT (NB*NH*DV*(KPAD/8))      // 8-elem groups in vT
__global__ void bn_normalize(bf16* __restrict__ qkv, bf16* __restrict__ vT,
                             const float* __restrict__ sb)
{
  const int stride = gridDim.x * blockDim.x;
  for (int i = blockIdx.x * blockDim.x + threadIdx.x; i < NQK + NVT; i += stride) {
    if (i < NQK) {
      int row = i / (NH*16);
      int gp = i - row*(NH*16);
      int f = (gp >> 4)*256 + (gp & 15)*8;
      bf16* p = qkv + (size_t)row*HQKV + f;
      u16x4 a = *(const u16x4*)p;
      u16x4 c = *(const u16x4*)(p + 4);
      f32x4 s0 = *(const f32x4*)&sb[f],        s1 = *(const f32x4*)&sb[f + 4];
      f32x4 b0 = *(const f32x4*)&sb[HQKV + f], b1 = *(const f32x4*)&sb[HQKV + f + 4];
      u16x4 oa, oc;
#pragma unroll
      for (int j = 0; j < 4; ++j) {
        oa[j] = f2bfu(u2f(a[j]) * s0[j] + b0[j]);
        oc[j] = f2bfu(u2f(c[j]) * s1[j] + b1[j]);
      }
      *(u16x4*)p = oa;
      *(u16x4*)(p + 4) = oc;
    } else {
      int k = i - NQK;
      int r = k / (KPAD/8);
      int gp = k - r*(KPAD/8);
      int d = r & 127;
      int h = (r >> 7) % NH;
      int f = h*256 + 128 + d;
      float scl = sb[f], bia = sb[HQKV + f];
      bf16* p = vT + (size_t)r*KPAD + gp*8;
      u16x4 a = *(const u16x4*)p;
      u16x4 c = *(const u16x4*)(p + 4);
      u16x4 oa, oc;
#pragma unroll
      for (int j = 0; j < 4; ++j) {
        oa[j] = f2bfu(u2f(a[j]) * scl + bia);
        oc[j] = f2bfu(u2f(c[j]) * scl + bia);
      }
      *(u16x4*)p = oa;
      *(u16x4*)(p + 4) = oc;
    }
  }
}

// ---------------- attention: 4 independent waves/block, 16 queries each ----------------
// Operands pre-normalized; Q/K/V^T MFMA fragments gathered directly from global (L2-resident).
// Only per-wave P tile in LDS. No __syncthreads.
__global__ __launch_bounds__(256, 3)
void attn_kernel(const bf16* __restrict__ qkv, const bf16* __restrict__ vT,
                 bf16* __restrict__ act, float* __restrict__ cls)
{
  __shared__ bf16 p_all[4*16*PSTR];   // 29.7 KB
  const int t = threadIdx.x;
  const int wave = t >> 6, lane = t & 63;
  const int l15 = lane & 15, l4 = lane >> 4;
  // qc-major-last mapping: 4 qc-blocks of one (b,h) land on the same XCD (bid % 8 equal)
  const int qc = blockIdx.x / (NB*NH);
  const int bh = blockIdx.x % (NB*NH);
  const int b = bh / NH, h = bh - b*NH;
  const size_t rowBase = (size_t)b * NT;
  bf16* p_lds = &p_all[wave * (16*PSTR)];
  const bf16* Qp = qkv + rowBase*HQKV + h*256;
  const bf16* Kp = Qp + 64;
  const bf16* Vp = vT + (size_t)bh*DV*KPAD;
  const int q0 = qc*64 + wave*16;

  s16x8 aq0 = *(const s16x8*)&Qp[(size_t)(q0 + l15)*HQKV + l4*8];
  s16x8 aq1 = *(const s16x8*)&Qp[(size_t)(q0 + l15)*HQKV + 32 + l4*8];

  // QK^T: 16 queries x 224 keys (K frags straight from global)
  f32x4 scr[14];
#pragma unroll
  for (int kt = 0; kt < 14; ++kt) {
    s16x8 bk0 = *(const s16x8*)&Kp[(size_t)(kt*16 + l15)*HQKV + l4*8];
    s16x8 bk1 = *(const s16x8*)&Kp[(size_t)(kt*16 + l15)*HQKV + 32 + l4*8];
    f32x4 z = {};
    z = __builtin_amdgcn_mfma_f32_16x16x32_bf16(aq0, bk0, z, 0, 0, 0);
    scr[kt] = __builtin_amdgcn_mfma_f32_16x16x32_bf16(aq1, bk1, z, 0, 0, 0);
  }

  // softmax: D rows (l4*4+j) = queries, cols (kt*16+l15) = keys
  float mx[4] = {-1e30f, -1e30f, -1e30f, -1e30f}, sm[4];
#pragma unroll
  for (int kt = 0; kt < 14; ++kt) {
    int colv = kt*16 + l15;
#pragma unroll
    for (int j = 0; j < 4; ++j) {
      if (colv >= NT) scr[kt][j] = -1e30f;
      mx[j] = fmaxf(mx[j], scr[kt][j]);
    }
  }
#pragma unroll
  for (int j = 0; j < 4; ++j) {
    mx[j] = fmaxf(mx[j], __shfl_xor(mx[j], 1));
    mx[j] = fmaxf(mx[j], __shfl_xor(mx[j], 2));
    mx[j] = fmaxf(mx[j], __shfl_xor(mx[j], 4));
    mx[j] = fmaxf(mx[j], __shfl_xor(mx[j], 8));
    sm[j] = 0.f;
  }
#pragma unroll
  for (int kt = 0; kt < 14; ++kt)
#pragma unroll
    for (int j = 0; j < 4; ++j) { float e = __expf(scr[kt][j] - mx[j]); scr[kt][j] = e; sm[j] += e; }
#pragma unroll
  for (int j = 0; j < 4; ++j) {
    sm[j] += __shfl_xor(sm[j], 1);
    sm[j] += __shfl_xor(sm[j], 2);
    sm[j] += __shfl_xor(sm[j], 4);
    sm[j] += __shfl_xor(sm[j], 8);
    sm[j] = 1.f / sm[j];
  }
  // cls-row reduction: query 0 is row 0 of (qc==0, wave==0)
  if (qc == 0 && wave == 0 && l4 == 0) {
#pragma unroll
    for (int kt = 0; kt < 14; ++kt) {
      int colv = kt*16 + l15;
      if (colv >= 1 && colv < NT)
        atomicAdd(&cls[b*(NT-1) + colv - 1], scr[kt][0] * sm[0] * (1.f/NH));
    }
  }
  // P -> per-wave LDS tile
#pragma unroll
  for (int kt = 0; kt < 14; ++kt) {
    int colv = kt*16 + l15;
#pragma unroll
    for (int j = 0; j < 4; ++j)
      p_lds[(l4*4 + j)*PSTR + colv] = f2bf(scr[kt][j] * sm[j]);
  }

  // PV: 16q x 128d; V^T frags straight from global; masked keys have p==0 exactly
  f32x4 ao[8] = {};
#pragma unroll
  for (int ks = 0; ks < 7; ++ks) {
    s16x8 ap = *(const s16x8*)&p_lds[l15*PSTR + ks*32 + l4*8];
#pragma unroll
    for (int dt = 0; dt < 8; ++dt) {
      s16x8 bv = *(const s16x8*)&Vp[(size_t)(dt*16 + l15)*KPAD + ks*32 + l4*8];
      ao[dt] = __builtin_amdgcn_mfma_f32_16x16x32_bf16(ap, bv, ao[dt], 0, 0, 0);
    }
  }
#pragma unroll
  for (int dt = 0; dt < 8; ++dt) {
#pragma unroll
    for (int j = 0; j < 4; ++j) {
      int q = q0 + l4*4 + j;
      if (q < NT) {
        float v = ao[dt][j];
        float hs = v * fminf(fmaxf(v + 3.f, 0.f), 6.f) * (1.f/6.f);
        act[(rowBase + q)*DH + h*DV + dt*16 + l15] = f2bf(hs);
      }
    }
  }
}

// ---------------- final BN apply -> f32 out ----------------
__global__ void apply_bn(const bf16* __restrict__ y, const float* __restrict__ sb,
                         float* __restrict__ out)
{
  const int stride = gridDim.x * blockDim.x;
  for (int i = blockIdx.x * blockDim.x + threadIdx.x; i < MREAL*DIM/4; i += stride) {
    int c = (i*4) % DIM;
    u16x4 yv = *(const u16x4*)&y[(size_t)i*4];
    float4 o;
    o.x = u2f(yv.x) * sb[c]     + sb[DIM + c];
    o.y = u2f(yv.y) * sb[c + 1] + sb[DIM + c + 1];
    o.z = u2f(yv.z) * sb[c + 2] + sb[DIM + c + 2];
    o.w = u2f(yv.w) * sb[c + 3] + sb[DIM + c + 3];
    *(float4*)&out[(size_t)i*4] = o;
  }
}

extern "C" void kernel_launch(void* const* d_in, const int* in_sizes, int n_in,
                              void* d_out, int out_size, void* d_ws, size_t ws_size,
                              hipStream_t stream)
{
  const float* x      = (const float*)d_in[0];
  const float* qkv_w  = (const float*)d_in[1];
  const float* qkv_g  = (const float*)d_in[2];
  const float* qkv_b  = (const float*)d_in[3];
  const float* proj_w = (const float*)d_in[4];
  const float* proj_g = (const float*)d_in[5];
  const float* proj_b = (const float*)d_in[6];
  float* y_out   = (float*)d_out;
  float* cls_out = y_out + (size_t)MREAL * DIM;

  char* ws = (char*)d_ws;
  size_t off = 0;
  auto alloc = [&](size_t bytes) { void* p = ws + off; off += (bytes + 255) & ~(size_t)255; return p; };
  bf16* xb      = (bf16*)alloc((size_t)MPAD * DIM * 2);
  bf16* wqkvb   = (bf16*)alloc((size_t)HQKV * DIM * 2);
  bf16* wprojb  = (bf16*)alloc((size_t)DIM * DH * 2);
  bf16* qkv_raw = (bf16*)alloc((size_t)MPAD * HQKV * 2);
  bf16* act     = (bf16*)alloc((size_t)MPAD * DH * 2);
  bf16* y_raw   = (bf16*)alloc((size_t)MPAD * DIM * 2);
  bf16* vT      = (bf16*)alloc((size_t)NB * NH * DV * KPAD * 2);
  float* statq  = (float*)alloc((size_t)2 * HQKV * 4);
  float* sbq    = (float*)alloc((size_t)2 * HQKV * 4);
  float* statp  = (float*)alloc((size_t)2 * DIM * 4);
  float* sbp    = (float*)alloc((size_t)2 * DIM * 4);

  prep_kernel<<<1024, 256, 0, stream>>>(x, qkv_w, proj_w, xb, wqkvb, wprojb, act, vT,
                                        statq, statp, cls_out);
  gemm_bt<DIM, HQKV/128, true><<<(MPAD/128)*(HQKV/128), 256, 0, stream>>>(xb, wqkvb, qkv_raw, vT, statq, HQKV);
  finalize_stats<<<HQKV/256, 256, 0, stream>>>(statq, qkv_g, qkv_b, sbq, HQKV, 1);
  bn_normalize<<<2048, 256, 0, stream>>>(qkv_raw, vT, sbq);
  attn_kernel<<<NB*NH*4, 256, 0, stream>>>(qkv_raw, vT, act, cls_out);
  gemm_bt<DH, DIM/128, false><<<(MPAD/128)*(DIM/128), 256, 0, stream>>>(act, wprojb, y_raw, nullptr, statp, DIM);
  finalize_stats<<<DIM/256, 256, 0, stream>>>(statp, proj_g, proj_b, sbp, DIM, 0);
  apply_bn<<<2048, 256, 0, stream>>>(y_raw, sbp, y_out);
}